// Round 1
// baseline (441.287 us; speedup 1.0000x reference)
//
#include <hip/hip_runtime.h>

#define N_NODES 50000
#define N_EDGES 1600000
#define F 64
#define G_GRAPHS 64
#define C_CLS 5
#define SLOPE 0.2f

#define SCAN_N (N_NODES + 1)
#define SCAN_NB ((SCAN_N + 255) / 256)

// ---------------- CSR build ----------------

__global__ void count_kernel(const int* __restrict__ dst, int* __restrict__ cnt) {
    int e = blockIdx.x * blockDim.x + threadIdx.x;
    if (e < N_EDGES) atomicAdd(&cnt[dst[e]], 1);
}

__global__ void partial_sum_kernel(const int* __restrict__ cnt, int* __restrict__ bsum) {
    __shared__ int sdata[256];
    int i = blockIdx.x * 256 + threadIdx.x;
    int v = (i < SCAN_N) ? cnt[i] : 0;
    sdata[threadIdx.x] = v;
    __syncthreads();
    for (int s = 128; s > 0; s >>= 1) {
        if (threadIdx.x < s) sdata[threadIdx.x] += sdata[threadIdx.x + s];
        __syncthreads();
    }
    if (threadIdx.x == 0) bsum[blockIdx.x] = sdata[0];
}

__global__ void scan_bsum_kernel(int* __restrict__ bsum) {
    if (threadIdx.x == 0 && blockIdx.x == 0) {
        int acc = 0;
        for (int i = 0; i < SCAN_NB; i++) { int v = bsum[i]; bsum[i] = acc; acc += v; }
    }
}

__global__ void scan_block_kernel(const int* __restrict__ cnt, const int* __restrict__ bsum,
                                  int* __restrict__ row_ptr) {
    __shared__ int sdata[256];
    int i = blockIdx.x * 256 + threadIdx.x;
    int v = (i < SCAN_N) ? cnt[i] : 0;
    sdata[threadIdx.x] = v;
    __syncthreads();
    // Hillis-Steele inclusive scan
    for (int s = 1; s < 256; s <<= 1) {
        int t = (threadIdx.x >= (unsigned)s) ? sdata[threadIdx.x - s] : 0;
        __syncthreads();
        sdata[threadIdx.x] += t;
        __syncthreads();
    }
    if (i < SCAN_N) row_ptr[i] = bsum[blockIdx.x] + sdata[threadIdx.x] - v;  // exclusive
}

__global__ void scatter_kernel(const int* __restrict__ src, const int* __restrict__ dst,
                               const int* __restrict__ row_ptr, int* __restrict__ cursor,
                               int* __restrict__ csr_src) {
    int e = blockIdx.x * blockDim.x + threadIdx.x;
    if (e < N_EDGES) {
        int d = dst[e];
        int pos = atomicAdd(&cursor[d], 1);
        csr_src[row_ptr[d] + pos] = src[e];
    }
}

// ---------------- fused GEMM + attention dots ----------------
// H = X @ W ; S = H @ a_s ; D = H @ a_d   (wave = row, lane = feature)

__global__ __launch_bounds__(256) void gemm_sd_kernel(
    const float* __restrict__ X, const float* __restrict__ W,
    const float* __restrict__ a_s, const float* __restrict__ a_d,
    float* __restrict__ H, float* __restrict__ S, float* __restrict__ D) {
    __shared__ float Wl[F * F];
    __shared__ float as_l[F], ad_l[F];
    for (int i = threadIdx.x; i < F * F; i += 256) Wl[i] = W[i];
    if (threadIdx.x < F) { as_l[threadIdx.x] = a_s[threadIdx.x]; ad_l[threadIdx.x] = a_d[threadIdx.x]; }
    __syncthreads();
    int lane = threadIdx.x & 63;
    int wid  = threadIdx.x >> 6;
    int gw   = blockIdx.x * 4 + wid;
    int nw   = gridDim.x * 4;
    for (int r = gw; r < N_NODES; r += nw) {
        float x = X[r * F + lane];
        float acc = 0.f;
        #pragma unroll
        for (int k = 0; k < F; k++) {
            float xk = __shfl(x, k, 64);
            acc = fmaf(xk, Wl[k * F + lane], acc);
        }
        H[r * F + lane] = acc;
        float sv = acc * as_l[lane];
        float dv = acc * ad_l[lane];
        #pragma unroll
        for (int o = 32; o > 0; o >>= 1) {
            sv += __shfl_down(sv, o, 64);
            dv += __shfl_down(dv, o, 64);
        }
        if (lane == 0) { S[r] = sv; D[r] = dv; }
    }
}

// ---------------- per-node softmax aggregation ----------------
// one wave per node; self-loop handled analytically

__global__ __launch_bounds__(256) void agg_kernel(
    const float* __restrict__ H, const float* __restrict__ S, const float* __restrict__ Dv,
    const int* __restrict__ row_ptr, const int* __restrict__ csr_src,
    const float* __restrict__ bias, float* __restrict__ OUT) {
    int lane = threadIdx.x & 63;
    int i = (blockIdx.x * blockDim.x + threadIdx.x) >> 6;
    if (i >= N_NODES) return;
    int start = row_ptr[i], end = row_ptr[i + 1];
    float d_i = Dv[i];
    float eself = S[i] + d_i;
    eself = eself > 0.f ? eself : SLOPE * eself;
    // phase 1: max over edges (edge per lane)
    float m = eself;
    for (int j = start + lane; j < end; j += 64) {
        float e = S[csr_src[j]] + d_i;
        e = e > 0.f ? e : SLOPE * e;
        m = fmaxf(m, e);
    }
    #pragma unroll
    for (int o = 32; o > 0; o >>= 1) m = fmaxf(m, __shfl_xor(m, o, 64));
    // phase 2: serial over edges, feature per lane
    float p = expf(eself - m);
    float z = p;
    float acc = p * H[i * F + lane];
    #pragma unroll 4
    for (int j = start; j < end; j++) {
        int sj = csr_src[j];
        float e = S[sj] + d_i;
        e = e > 0.f ? e : SLOPE * e;
        float pj = expf(e - m);
        z += pj;
        acc = fmaf(pj, H[sj * F + lane], acc);
    }
    float o = acc / z + bias[lane];
    OUT[i * F + lane] = fmaxf(o, 0.f);  // both layers have ReLU after
}

// ---------------- global max pool (batch is sorted) ----------------

__global__ __launch_bounds__(256) void pool_kernel(
    const float* __restrict__ H, const int* __restrict__ batch, float* __restrict__ gmax) {
    int lane = threadIdx.x & 63;
    int gw = (blockIdx.x * blockDim.x + threadIdx.x) >> 6;
    int nw = (gridDim.x * blockDim.x) >> 6;
    int per = (N_NODES + nw - 1) / nw;
    int s = gw * per;
    int e = min(N_NODES, s + per);
    if (s >= e) return;
    int curb = batch[s];
    float mx = H[s * F + lane];
    for (int i = s + 1; i < e; i++) {
        int b = batch[i];
        float v = H[i * F + lane];
        if (b != curb) {
            atomicMax((int*)&gmax[curb * F + lane], __float_as_int(mx));
            curb = b; mx = v;
        } else {
            mx = fmaxf(mx, v);
        }
    }
    atomicMax((int*)&gmax[curb * F + lane], __float_as_int(mx));
}

// ---------------- final linear ----------------

__global__ void final_kernel(const float* __restrict__ gmax, const float* __restrict__ Wl,
                             const float* __restrict__ bl, float* __restrict__ out) {
    int g = blockIdx.x;
    int c = threadIdx.x;
    if (c < C_CLS) {
        float acc = bl[c];
        #pragma unroll
        for (int f = 0; f < F; f++) acc = fmaf(gmax[g * F + f], Wl[f * C_CLS + c], acc);
        out[g * C_CLS + c] = acc;
    }
}

// ---------------- launch ----------------

extern "C" void kernel_launch(void* const* d_in, const int* in_sizes, int n_in,
                              void* d_out, int out_size, void* d_ws, size_t ws_size,
                              hipStream_t stream) {
    const float* x    = (const float*)d_in[0];
    const int*   ei   = (const int*)d_in[1];
    const int*   batch= (const int*)d_in[2];
    const float* W1   = (const float*)d_in[3];
    const float* a1s  = (const float*)d_in[4];
    const float* a1d  = (const float*)d_in[5];
    const float* b1   = (const float*)d_in[6];
    const float* W2   = (const float*)d_in[7];
    const float* a2s  = (const float*)d_in[8];
    const float* a2d  = (const float*)d_in[9];
    const float* b2   = (const float*)d_in[10];
    const float* Wl   = (const float*)d_in[11];
    const float* bl   = (const float*)d_in[12];
    float* out = (float*)d_out;

    const int* src = ei;
    const int* dst = ei + N_EDGES;

    // workspace layout (256B aligned)
    char* ws = (char*)d_ws;
    size_t off = 0;
    auto alloc = [&](size_t bytes) { size_t o = off; off += (bytes + 255) & ~(size_t)255; return o; };
    int*   cnt     = (int*)(ws + alloc((size_t)SCAN_N * 4));      // also reused as scatter cursor
    int*   row_ptr = (int*)(ws + alloc((size_t)SCAN_N * 4));
    int*   bsum    = (int*)(ws + alloc((size_t)SCAN_NB * 4));
    int*   csr_src = (int*)(ws + alloc((size_t)N_EDGES * 4));
    float* hA      = (float*)(ws + alloc((size_t)N_NODES * F * 4));
    float* hB      = (float*)(ws + alloc((size_t)N_NODES * F * 4));
    float* Sv      = (float*)(ws + alloc((size_t)N_NODES * 4));
    float* Dv      = (float*)(ws + alloc((size_t)N_NODES * 4));
    float* gmax    = (float*)(ws + alloc((size_t)G_GRAPHS * F * 4));

    // ---- CSR build ----
    hipMemsetAsync(cnt, 0, (size_t)SCAN_N * 4, stream);
    count_kernel<<<(N_EDGES + 255) / 256, 256, 0, stream>>>(dst, cnt);
    partial_sum_kernel<<<SCAN_NB, 256, 0, stream>>>(cnt, bsum);
    scan_bsum_kernel<<<1, 64, 0, stream>>>(bsum);
    scan_block_kernel<<<SCAN_NB, 256, 0, stream>>>(cnt, bsum, row_ptr);
    hipMemsetAsync(cnt, 0, (size_t)SCAN_N * 4, stream);
    scatter_kernel<<<(N_EDGES + 255) / 256, 256, 0, stream>>>(src, dst, row_ptr, cnt, csr_src);

    // ---- layer 1 ----
    gemm_sd_kernel<<<1024, 256, 0, stream>>>(x, W1, a1s, a1d, hA, Sv, Dv);
    agg_kernel<<<(N_NODES * 64 + 255) / 256, 256, 0, stream>>>(hA, Sv, Dv, row_ptr, csr_src, b1, hB);

    // ---- layer 2 ----
    gemm_sd_kernel<<<1024, 256, 0, stream>>>(hB, W2, a2s, a2d, hA, Sv, Dv);
    agg_kernel<<<(N_NODES * 64 + 255) / 256, 256, 0, stream>>>(hA, Sv, Dv, row_ptr, csr_src, b2, hB);

    // ---- pool + classifier ----
    hipMemsetAsync(gmax, 0, (size_t)G_GRAPHS * F * 4, stream);
    pool_kernel<<<512, 256, 0, stream>>>(hB, batch, gmax);
    final_kernel<<<G_GRAPHS, 64, 0, stream>>>(gmax, Wl, bl, out);
}

// Round 2
// 362.267 us; speedup vs baseline: 1.2181x; 1.2181x over previous
//
#include <hip/hip_runtime.h>

#define N_NODES 50000
#define N_EDGES 1600000
#define F 64
#define G_GRAPHS 64
#define C_CLS 5
#define SLOPE 0.2f

#define NBUCKET ((N_NODES + 127) >> 7)   // 391 buckets of 128 nodes
#define ACHUNK 2048
#define NCHUNKS ((N_EDGES + ACHUNK - 1) / ACHUNK)
#define CAP 8192                          // max edges per bucket (mean 4092, std 64)

// ---------------- CSR build: bucketed counting sort ----------------

__global__ __launch_bounds__(256) void bucket_count(const int* __restrict__ dst,
                                                    int* __restrict__ gcount) {
    __shared__ int hist[NBUCKET];
    int tid = threadIdx.x;
    for (int i = tid; i < NBUCKET; i += 256) hist[i] = 0;
    __syncthreads();
    int base = blockIdx.x * ACHUNK;
    int lim = min(ACHUNK, N_EDGES - base);
    for (int t = tid; t < lim; t += 256) atomicAdd(&hist[dst[base + t] >> 7], 1);
    __syncthreads();
    for (int i = tid; i < NBUCKET; i += 256)
        if (hist[i]) atomicAdd(&gcount[i], hist[i]);
}

__global__ __launch_bounds__(512) void scan_buckets(const int* __restrict__ gcount,
                                                    int* __restrict__ bucket_base) {
    __shared__ int sc[512];
    int tid = threadIdx.x;
    int v = (tid < NBUCKET) ? gcount[tid] : 0;
    sc[tid] = v;
    __syncthreads();
    for (int s = 1; s < 512; s <<= 1) {
        int t = (tid >= s) ? sc[tid - s] : 0;
        __syncthreads();
        sc[tid] += t;
        __syncthreads();
    }
    if (tid < NBUCKET) bucket_base[tid] = sc[tid] - v;   // exclusive
}

__global__ __launch_bounds__(256) void bucket_scatter(
    const int* __restrict__ src, const int* __restrict__ dst,
    const int* __restrict__ bucket_base, int* __restrict__ gcursor,
    unsigned long long* __restrict__ bedges) {
    __shared__ int hist[NBUCKET];
    __shared__ int resv[NBUCKET];
    __shared__ int cur[NBUCKET];
    int tid = threadIdx.x;
    for (int i = tid; i < NBUCKET; i += 256) { hist[i] = 0; cur[i] = 0; }
    __syncthreads();
    int base = blockIdx.x * ACHUNK;
    int lim = min(ACHUNK, N_EDGES - base);
    for (int t = tid; t < lim; t += 256) atomicAdd(&hist[dst[base + t] >> 7], 1);
    __syncthreads();
    for (int i = tid; i < NBUCKET; i += 256)
        if (hist[i]) resv[i] = atomicAdd(&gcursor[i], hist[i]);
    __syncthreads();
    for (int t = tid; t < lim; t += 256) {
        int e = base + t;
        int d = dst[e];
        int b = d >> 7;
        int r = atomicAdd(&cur[b], 1);
        bedges[bucket_base[b] + resv[b] + r] =
            ((unsigned long long)(unsigned)(d & 127) << 32) | (unsigned)src[e];
    }
}

__global__ __launch_bounds__(256) void bucket_csr(
    const unsigned long long* __restrict__ bedges, const int* __restrict__ gcount,
    const int* __restrict__ bucket_base, int* __restrict__ row_ptr,
    int* __restrict__ csr_src) {
    __shared__ int hist[128];
    __shared__ int sc[128];
    __shared__ int loff[129];
    __shared__ int cur[128];
    __shared__ int outs[CAP];
    int tid = threadIdx.x;
    int b = blockIdx.x;
    int nbase = b << 7;
    int nlocal = min(128, N_NODES - nbase);
    int cnt = min(gcount[b], CAP);
    int cbase = bucket_base[b];
    if (tid < 128) { hist[tid] = 0; cur[tid] = 0; }
    __syncthreads();
    for (int t = tid; t < cnt; t += 256)
        atomicAdd(&hist[(int)(bedges[cbase + t] >> 32)], 1);
    __syncthreads();
    if (tid < 128) sc[tid] = hist[tid];
    __syncthreads();
    for (int s = 1; s < 128; s <<= 1) {
        int t = (tid < 128 && tid >= s) ? sc[tid - s] : 0;
        __syncthreads();
        if (tid < 128) sc[tid] += t;
        __syncthreads();
    }
    if (tid < 128) loff[tid + 1] = sc[tid];
    if (tid == 0) loff[0] = 0;
    __syncthreads();
    for (int t = tid; t < cnt; t += 256) {
        unsigned long long p = bedges[cbase + t];
        int dl = (int)(p >> 32);
        int r = atomicAdd(&cur[dl], 1);
        outs[loff[dl] + r] = (int)(unsigned)p;
    }
    __syncthreads();
    for (int t = tid; t < cnt; t += 256) csr_src[cbase + t] = outs[t];
    for (int i = tid; i < nlocal; i += 256) row_ptr[nbase + i] = cbase + loff[i];
    if (b == NBUCKET - 1 && tid == 0) row_ptr[N_NODES] = cbase + loff[nlocal];
}

// ---------------- fused GEMM + attention dots ----------------
// H = X @ W ; S = H @ a_s ; D = H @ a_d   (wave = row, lane = feature)

__global__ __launch_bounds__(256) void gemm_sd_kernel(
    const float* __restrict__ X, const float* __restrict__ W,
    const float* __restrict__ a_s, const float* __restrict__ a_d,
    float* __restrict__ H, float* __restrict__ S, float* __restrict__ D) {
    __shared__ float Wl[F * F];
    __shared__ float as_l[F], ad_l[F];
    for (int i = threadIdx.x; i < F * F; i += 256) Wl[i] = W[i];
    if (threadIdx.x < F) { as_l[threadIdx.x] = a_s[threadIdx.x]; ad_l[threadIdx.x] = a_d[threadIdx.x]; }
    __syncthreads();
    int lane = threadIdx.x & 63;
    int wid  = threadIdx.x >> 6;
    int gw   = blockIdx.x * 4 + wid;
    int nw   = gridDim.x * 4;
    for (int r = gw; r < N_NODES; r += nw) {
        float x = X[r * F + lane];
        float acc = 0.f;
        #pragma unroll
        for (int k = 0; k < F; k++) {
            float xk = __shfl(x, k, 64);
            acc = fmaf(xk, Wl[k * F + lane], acc);
        }
        H[r * F + lane] = acc;
        float sv = acc * as_l[lane];
        float dv = acc * ad_l[lane];
        #pragma unroll
        for (int o = 32; o > 0; o >>= 1) {
            sv += __shfl_down(sv, o, 64);
            dv += __shfl_down(dv, o, 64);
        }
        if (lane == 0) { S[r] = sv; D[r] = dv; }
    }
}

// ---------------- per-node softmax aggregation ----------------
// one wave per node; self-loop handled analytically

__global__ __launch_bounds__(256) void agg_kernel(
    const float* __restrict__ H, const float* __restrict__ S, const float* __restrict__ Dv,
    const int* __restrict__ row_ptr, const int* __restrict__ csr_src,
    const float* __restrict__ bias, float* __restrict__ OUT) {
    int lane = threadIdx.x & 63;
    int i = (blockIdx.x * blockDim.x + threadIdx.x) >> 6;
    if (i >= N_NODES) return;
    int start = row_ptr[i], end = row_ptr[i + 1];
    float d_i = Dv[i];
    float eself = S[i] + d_i;
    eself = eself > 0.f ? eself : SLOPE * eself;
    // phase 1: max over edges (edge per lane)
    float m = eself;
    for (int j = start + lane; j < end; j += 64) {
        float e = S[csr_src[j]] + d_i;
        e = e > 0.f ? e : SLOPE * e;
        m = fmaxf(m, e);
    }
    #pragma unroll
    for (int o = 32; o > 0; o >>= 1) m = fmaxf(m, __shfl_xor(m, o, 64));
    // phase 2: serial over edges, feature per lane
    float p = expf(eself - m);
    float z = p;
    float acc = p * H[i * F + lane];
    #pragma unroll 4
    for (int j = start; j < end; j++) {
        int sj = csr_src[j];
        float e = S[sj] + d_i;
        e = e > 0.f ? e : SLOPE * e;
        float pj = expf(e - m);
        z += pj;
        acc = fmaf(pj, H[sj * F + lane], acc);
    }
    float o = acc / z + bias[lane];
    OUT[i * F + lane] = fmaxf(o, 0.f);  // both layers have ReLU after
}

// ---------------- global max pool (batch is sorted) ----------------

__global__ __launch_bounds__(256) void pool_kernel(
    const float* __restrict__ H, const int* __restrict__ batch, float* __restrict__ gmax) {
    int lane = threadIdx.x & 63;
    int gw = (blockIdx.x * blockDim.x + threadIdx.x) >> 6;
    int nw = (gridDim.x * blockDim.x) >> 6;
    int per = (N_NODES + nw - 1) / nw;
    int s = gw * per;
    int e = min(N_NODES, s + per);
    if (s >= e) return;
    int curb = batch[s];
    float mx = H[s * F + lane];
    for (int i = s + 1; i < e; i++) {
        int b = batch[i];
        float v = H[i * F + lane];
        if (b != curb) {
            atomicMax((int*)&gmax[curb * F + lane], __float_as_int(mx));
            curb = b; mx = v;
        } else {
            mx = fmaxf(mx, v);
        }
    }
    atomicMax((int*)&gmax[curb * F + lane], __float_as_int(mx));
}

// ---------------- final linear ----------------

__global__ void final_kernel(const float* __restrict__ gmax, const float* __restrict__ Wl,
                             const float* __restrict__ bl, float* __restrict__ out) {
    int g = blockIdx.x;
    int c = threadIdx.x;
    if (c < C_CLS) {
        float acc = bl[c];
        #pragma unroll
        for (int f = 0; f < F; f++) acc = fmaf(gmax[g * F + f], Wl[f * C_CLS + c], acc);
        out[g * C_CLS + c] = acc;
    }
}

// ---------------- launch ----------------

extern "C" void kernel_launch(void* const* d_in, const int* in_sizes, int n_in,
                              void* d_out, int out_size, void* d_ws, size_t ws_size,
                              hipStream_t stream) {
    const float* x    = (const float*)d_in[0];
    const int*   ei   = (const int*)d_in[1];
    const int*   batch= (const int*)d_in[2];
    const float* W1   = (const float*)d_in[3];
    const float* a1s  = (const float*)d_in[4];
    const float* a1d  = (const float*)d_in[5];
    const float* b1   = (const float*)d_in[6];
    const float* W2   = (const float*)d_in[7];
    const float* a2s  = (const float*)d_in[8];
    const float* a2d  = (const float*)d_in[9];
    const float* b2   = (const float*)d_in[10];
    const float* Wl   = (const float*)d_in[11];
    const float* bl   = (const float*)d_in[12];
    float* out = (float*)d_out;

    const int* src = ei;
    const int* dst = ei + N_EDGES;

    // workspace layout (256B aligned)
    char* ws = (char*)d_ws;
    size_t off = 0;
    auto alloc = [&](size_t bytes) { size_t o = off; off += (bytes + 255) & ~(size_t)255; return o; };
    int*   row_ptr = (int*)(ws + alloc((size_t)(N_NODES + 1) * 4));
    int*   csr_src = (int*)(ws + alloc((size_t)N_EDGES * 4));
    // bedges (E*8 = 12.8MB) aliases hA (N*F*4 = 12.8MB): bedges is dead before hA is first written
    char*  hAbed   = ws + alloc((size_t)N_EDGES * 8);
    unsigned long long* bedges = (unsigned long long*)hAbed;
    float* hA      = (float*)hAbed;
    float* hB      = (float*)(ws + alloc((size_t)N_NODES * F * 4));
    float* Sv      = (float*)(ws + alloc((size_t)N_NODES * 4));
    float* Dv      = (float*)(ws + alloc((size_t)N_NODES * 4));
    float* gmax    = (float*)(ws + alloc((size_t)G_GRAPHS * F * 4));
    int*   bmeta   = (int*)(ws + alloc((size_t)3 * NBUCKET * 4));
    int*   gcount  = bmeta;
    int*   gcursor = bmeta + NBUCKET;
    int*   bucket_base = bmeta + 2 * NBUCKET;

    // ---- CSR build (bucketed counting sort) ----
    hipMemsetAsync(bmeta, 0, (size_t)2 * NBUCKET * 4, stream);
    bucket_count<<<NCHUNKS, 256, 0, stream>>>(dst, gcount);
    scan_buckets<<<1, 512, 0, stream>>>(gcount, bucket_base);
    bucket_scatter<<<NCHUNKS, 256, 0, stream>>>(src, dst, bucket_base, gcursor, bedges);
    bucket_csr<<<NBUCKET, 256, 0, stream>>>(bedges, gcount, bucket_base, row_ptr, csr_src);

    // ---- layer 1 ----
    gemm_sd_kernel<<<1024, 256, 0, stream>>>(x, W1, a1s, a1d, hA, Sv, Dv);
    agg_kernel<<<(N_NODES * 64 + 255) / 256, 256, 0, stream>>>(hA, Sv, Dv, row_ptr, csr_src, b1, hB);

    // ---- layer 2 ----
    gemm_sd_kernel<<<1024, 256, 0, stream>>>(hB, W2, a2s, a2d, hA, Sv, Dv);
    agg_kernel<<<(N_NODES * 64 + 255) / 256, 256, 0, stream>>>(hA, Sv, Dv, row_ptr, csr_src, b2, hB);

    // ---- pool + classifier ----
    hipMemsetAsync(gmax, 0, (size_t)G_GRAPHS * F * 4, stream);
    pool_kernel<<<512, 256, 0, stream>>>(hB, batch, gmax);
    final_kernel<<<G_GRAPHS, 64, 0, stream>>>(gmax, Wl, bl, out);
}